// Round 9
// baseline (481.179 us; speedup 1.0000x reference)
//
#include <hip/hip_runtime.h>

// MHA forward: B=2, S=4096, D=768, H=12, Dh=64.
// gemm_qkv (A,B staged fp32, cvt on read) -> flash attention (swapped QK^T
// 32x32, KVBLK=32, kv-split x2 for 24 waves/CU, static-max exp2, ones-MFMA
// row-sum, permlane P) -> merge halves -> gemm_out (B staged fp32).

typedef __attribute__((ext_vector_type(4))) float f32x4;
typedef __attribute__((ext_vector_type(16))) float f32x16;
typedef __attribute__((ext_vector_type(8))) __bf16 bf16x8;
typedef __attribute__((ext_vector_type(2))) int i32x2;
typedef __attribute__((ext_vector_type(4))) unsigned u32x4;
using u16 = unsigned short;
using u32 = unsigned;

__device__ __forceinline__ u16 f2bf(float x) {
  __bf16 h = (__bf16)x;
  return __builtin_bit_cast(u16, h);
}
__device__ __forceinline__ u32 pk2(float lo, float hi) {  // v_cvt_pk_bf16_f32 (RNE)
  u32 r;
  asm("v_cvt_pk_bf16_f32 %0, %1, %2" : "=v"(r) : "v"(lo), "v"(hi));
  return r;
}
__device__ __forceinline__ void gload16(u16* ldsDst, const u16* gSrc) {
  __builtin_amdgcn_global_load_lds(
      (const __attribute__((address_space(1))) void*)gSrc,
      (__attribute__((address_space(3))) void*)ldsDst, 16, 0, 0);
}
__device__ __forceinline__ f32x4 mfma16(bf16x8 a, bf16x8 b, f32x4 c) {
  return __builtin_amdgcn_mfma_f32_16x16x32_bf16(a, b, c, 0, 0, 0);
}
__device__ __forceinline__ f32x16 mfma32(bf16x8 a, bf16x8 b, f32x16 c) {
  return __builtin_amdgcn_mfma_f32_32x32x16_bf16(a, b, c, 0, 0, 0);
}
__device__ __forceinline__ bf16x8 ld8(const u16* p) { return *(const bf16x8*)p; }

// ---------------------------------------------------------------- QKV projection GEMM
// C = A * B^T + bias.  A:[8192,768] fp32, B:[768,768] fp32 — both staged fp32,
// converted to bf16 on fragment read. z=0: qh (*qscale), z=1: kh, z=2: vt.
// LDS/buffer: A fp32 [128][32] 16KB | B fp32 [128][32] 16KB  => 64KB total.
__global__ __launch_bounds__(256, 2) void gemm_qkv(
    const float* __restrict__ Aq, const float* __restrict__ Ak,
    const float* __restrict__ Av,
    const float* __restrict__ Wq, const float* __restrict__ Wk,
    const float* __restrict__ Wv,
    const float* __restrict__ bq, const float* __restrict__ bk,
    const float* __restrict__ bv,
    u16* __restrict__ oq, u16* __restrict__ ok, u16* __restrict__ ov,
    float qscale) {
  constexpr int K = 768;
  constexpr int BUF = 16384;  // u16 units
  __shared__ __align__(16) u16 lds[2 * BUF];
  const int z = blockIdx.z;
  const float* A = (z == 0) ? Aq : (z == 1) ? Ak : Av;
  const float* Bf = (z == 0) ? Wq : (z == 1) ? Wk : Wv;
  const float* bias = (z == 0) ? bq : (z == 1) ? bk : bv;
  u16* C = (z == 0) ? oq : (z == 1) ? ok : ov;
  const float scale = (z == 0) ? qscale : 1.f;
  const bool vmode = (z == 2);

  const int tid = threadIdx.x, lane = tid & 63, w = tid >> 6;
  const int wr = w >> 1, wc = w & 1;
  const int g = lane >> 4, la = lane & 15;
  const int m0 = blockIdx.x * 128, n0 = blockIdx.y * 128;

  f32x4 acc[4][4] = {};

  // fp32 staging: slot i covers rows 8i..8i+7; lane r8=lane>>3, chunk c=(lane&7)^r8.
  auto stage = [&](int buf, int kt) {
    const int k0 = kt * 32;
    u16* base = &lds[buf * BUF];
    const int r8 = lane >> 3;
    const int c = (lane & 7) ^ r8;
#pragma unroll
    for (int j = 0; j < 4; ++j) {
      const int i = w * 4 + j;
      const int r = i * 8 + r8;
      gload16(base + i * 512, (const u16*)(A + (size_t)(m0 + r) * K + k0 + c * 4));
      gload16(base + 8192 + i * 512, (const u16*)(Bf + (size_t)(n0 + r) * K + k0 + c * 4));
    }
  };
  // fp32 fragment: 8 fp32 (k = gg*8..+8) from slots (2gg)^(r&7), (2gg+1)^(r&7).
  auto rdfragF = [&](const float* baseF, int row, int gg) -> bf16x8 {
    const int x = row & 7;
    const f32x4 u = *(const f32x4*)(baseF + row * 32 + (((2 * gg) ^ x) << 2));
    const f32x4 v = *(const f32x4*)(baseF + row * 32 + (((2 * gg + 1) ^ x) << 2));
    u32x4 wq_ = {pk2(u[0], u[1]), pk2(u[2], u[3]), pk2(v[0], v[1]), pk2(v[2], v[3])};
    return __builtin_bit_cast(bf16x8, wq_);
  };

  stage(0, 0);
  __syncthreads();
  constexpr int nk = K / 32;
  int cur = 0;
  for (int kt = 0; kt < nk; ++kt) {
    if (kt + 1 < nk) stage(cur ^ 1, kt + 1);
    const float* aF = (const float*)&lds[cur * BUF];
    const float* bF = (const float*)&lds[cur * BUF + 8192];
    bf16x8 aH[4], bH[4];
#pragma unroll
    for (int ni = 0; ni < 4; ++ni) bH[ni] = rdfragF(bF, wc * 64 + ni * 16 + la, g);
#pragma unroll
    for (int mi = 0; mi < 4; ++mi) aH[mi] = rdfragF(aF, wr * 64 + mi * 16 + la, g);
#pragma unroll
    for (int mi = 0; mi < 4; ++mi)
#pragma unroll
      for (int ni = 0; ni < 4; ++ni)
        acc[mi][ni] = mfma16(aH[mi], bH[ni], acc[mi][ni]);
    __syncthreads();
    cur ^= 1;
  }

#pragma unroll
  for (int mi = 0; mi < 4; ++mi) {
    const int mbase = m0 + wr * 64 + mi * 16 + g * 4;
#pragma unroll
    for (int ni = 0; ni < 4; ++ni) {
      const int n = n0 + wc * 64 + ni * 16 + la;
      const float bv_ = bias[n];
#pragma unroll
      for (int r = 0; r < 4; ++r) {
        const int m = mbase + r;
        const float y = (acc[mi][ni][r] + bv_) * scale;
        const int bb = m >> 12, s = m & 4095, hh = n >> 6, dh = n & 63;
        if (!vmode)
          C[((size_t)(bb * 12 + hh) * 4096 + s) * 64 + dh] = f2bf(y);
        else
          C[((size_t)(bb * 12 + hh) * 64 + dh) * 4096 + s] = f2bf(y);
      }
    }
  }
}

// ---------------------------------------------------------------- out-proj GEMM
// Cf = A(ctx bf16) * Wo^T + bo, fp32 out. B staged fp32, cvt on read.
// LDS/buffer: A bf16 8KB | B fp32 16KB => 48KB total.
__global__ __launch_bounds__(256, 2) void gemm_out(
    const u16* __restrict__ A, const float* __restrict__ Bf,
    const float* __restrict__ bias, float* __restrict__ Cf) {
  constexpr int K = 768, N = 768;
  constexpr int BUF = 12288;  // u16 units: A 4096 | B 8192
  __shared__ __align__(16) u16 lds[2 * BUF];
  const int tid = threadIdx.x, lane = tid & 63, w = tid >> 6;
  const int wr = w >> 1, wc = w & 1;
  const int g = lane >> 4, la = lane & 15;
  const int m0 = blockIdx.x * 128, n0 = blockIdx.y * 128;

  f32x4 acc[4][4] = {};

  auto stage = [&](int buf, int kt) {
    const int k0 = kt * 32;
    u16* base = &lds[buf * BUF];
#pragma unroll
    for (int j = 0; j < 2; ++j) {  // A bf16: 2-superrow pattern
      const int t = w * 2 + j;
      const int s = t * 64 + lane;
      const int sr = s >> 3, ph = s & 7, ch = ph ^ (sr & 7);
      const int row = sr * 2 + (ch >> 2), c = ch & 3;
      gload16(base + t * 512, A + (size_t)(m0 + row) * K + k0 + c * 8);
    }
    const int r8 = lane >> 3;
    const int c = (lane & 7) ^ r8;
#pragma unroll
    for (int j = 0; j < 4; ++j) {  // B fp32
      const int i = w * 4 + j;
      const int r = i * 8 + r8;
      gload16(base + 4096 + i * 512, (const u16*)(Bf + (size_t)(n0 + r) * K + k0 + c * 4));
    }
  };
  auto rdfragA = [&](const u16* base, int row, int c) -> bf16x8 {
    const int sr = row >> 1;
    const int ph = (((row & 1) << 2) | c) ^ (sr & 7);
    return ld8(base + sr * 64 + ph * 8);
  };
  auto rdfragF = [&](const float* baseF, int row, int gg) -> bf16x8 {
    const int x = row & 7;
    const f32x4 u = *(const f32x4*)(baseF + row * 32 + (((2 * gg) ^ x) << 2));
    const f32x4 v = *(const f32x4*)(baseF + row * 32 + (((2 * gg + 1) ^ x) << 2));
    u32x4 wq_ = {pk2(u[0], u[1]), pk2(u[2], u[3]), pk2(v[0], v[1]), pk2(v[2], v[3])};
    return __builtin_bit_cast(bf16x8, wq_);
  };

  stage(0, 0);
  __syncthreads();
  constexpr int nk = K / 32;
  int cur = 0;
  for (int kt = 0; kt < nk; ++kt) {
    if (kt + 1 < nk) stage(cur ^ 1, kt + 1);
    const u16* bA = &lds[cur * BUF];
    const float* bF = (const float*)&lds[cur * BUF + 4096];
    bf16x8 aH[4], bH[4];
#pragma unroll
    for (int mi = 0; mi < 4; ++mi) aH[mi] = rdfragA(bA, wr * 64 + mi * 16 + la, g);
#pragma unroll
    for (int ni = 0; ni < 4; ++ni) bH[ni] = rdfragF(bF, wc * 64 + ni * 16 + la, g);
#pragma unroll
    for (int mi = 0; mi < 4; ++mi)
#pragma unroll
      for (int ni = 0; ni < 4; ++ni)
        acc[mi][ni] = mfma16(aH[mi], bH[ni], acc[mi][ni]);
    __syncthreads();
    cur ^= 1;
  }

#pragma unroll
  for (int mi = 0; mi < 4; ++mi) {
    const int mbase = m0 + wr * 64 + mi * 16 + g * 4;
#pragma unroll
    for (int ni = 0; ni < 4; ++ni) {
      const int n = n0 + wc * 64 + ni * 16 + la;
      const float bv_ = bias[n];
#pragma unroll
      for (int r = 0; r < 4; ++r)
        Cf[(size_t)(mbase + r) * N + n] = acc[mi][ni][r] + bv_;
    }
  }
}

// ---------------------------------------------------------------- flash attention (kv-split)
// Swapped QK^T on 32x32x16; static max m=4; lp via ones-MFMA. KVBLK=32, LDS
// 16KB (K [32kv][64d] 4KB | V^T interleaved [32 rows of 128B: d | d+32] 4KB,
// double-buffered). Grid (32 qtiles, 24 bh, 2 kv-halves) = 1536 blocks =
// 6 blocks/CU = 24 waves/CU. Writes raw partial O (f32) + lp per half.
__global__ __launch_bounds__(256, 6) void flash_attn(
    const u16* __restrict__ Q, const u16* __restrict__ Kt,
    const u16* __restrict__ Vt, float* __restrict__ opart,
    float* __restrict__ lppart) {
  __shared__ __align__(16) u16 lds[2 * 4096];
  const int tid = threadIdx.x, lane = tid & 63, w = tid >> 6;
  const int l5 = lane & 31, hi = lane >> 5;
  const int bh = blockIdx.y, z = blockIdx.z;
  const int q0 = blockIdx.x * 128 + w * 32;
  const size_t kbase = (size_t)bh * 4096 * 64;
  const size_t vbase = (size_t)bh * 64 * 4096;
  const int ko = z * 2048;  // kv range [ko, ko+2048)

  bf16x8 aQ[4];
#pragma unroll
  for (int ks = 0; ks < 4; ++ks)
    aQ[ks] = ld8(Q + kbase + (size_t)(q0 + l5) * 64 + ks * 16 + hi * 8);

  f32x16 accO0 = {}, accO1 = {}, accLP = {};
  f32x16 M4;
#pragma unroll
  for (int i = 0; i < 16; ++i) M4[i] = -4.0f;
  const u32x4 onebits = {0x3F803F80u, 0x3F803F80u, 0x3F803F80u, 0x3F803F80u};
  const bf16x8 ones = __builtin_bit_cast(bf16x8, onebits);

  // LDS read offsets (u16, within one buffer). Row swizzle f0 = (l5&7)^(l5>>3).
  const int f0 = (l5 & 7) ^ (l5 >> 3);
  int aK0[4], aV0[2], aV1[2];
#pragma unroll
  for (int ks = 0; ks < 4; ++ks)
    aK0[ks] = l5 * 64 + (((ks * 2 + hi) ^ f0) << 3);
#pragma unroll
  for (int s2 = 0; s2 < 2; ++s2) {
    aV0[s2] = 2048 + l5 * 64 + (((s2 * 2 + hi) ^ f0) << 3);        // d = l5
    aV1[s2] = 2048 + l5 * 64 + (((4 + s2 * 2 + hi) ^ f0) << 3);    // d = 32+l5
  }

  // Staging (per wave: 1 K slot + 1 V slot of 1KB). Pre-swizzled global src.
  const u16 *gk, *gv;
  int dK, dV;
  {
    const int r = w * 8 + (lane >> 3);
    const int fr = (r & 7) ^ (r >> 3);
    const int cK = (lane & 7) ^ fr;
    gk = Kt + kbase + (size_t)(ko + r) * 64 + cK * 8;
    dK = w * 512;
    const int cp = (lane & 7) ^ fr;             // c' = half*4 + chunk
    const int dd = r + 32 * (cp >> 2), cc = cp & 3;
    gv = Vt + vbase + (size_t)dd * 4096 + ko + cc * 8;
    dV = 2048 + w * 512;
  }
  auto stage = [&](int B0, int tile) {
    gload16(&lds[B0 + dK], gk + (size_t)tile * 2048);
    gload16(&lds[B0 + dV], gv + tile * 32);
  };

  auto body = [&](const int B0) {
    f32x16 s0 = mfma32(ld8(&lds[B0 + aK0[0]]), aQ[0], M4);
#pragma unroll
    for (int ks = 1; ks < 4; ++ks)
      s0 = mfma32(ld8(&lds[B0 + aK0[ks]]), aQ[ks], s0);
    float p[16];
#pragma unroll
    for (int i = 0; i < 16; ++i) p[i] = __builtin_exp2f(s0[i]);
    u32 W[4][2];
#pragma unroll
    for (int qd = 0; qd < 4; ++qd) {
      W[qd][0] = pk2(p[qd * 4 + 0], p[qd * 4 + 1]);
      W[qd][1] = pk2(p[qd * 4 + 2], p[qd * 4 + 3]);
    }
#pragma unroll
    for (int s2 = 0; s2 < 2; ++s2) {
      i32x2 r1 = __builtin_amdgcn_permlane32_swap((int)W[2 * s2][0], (int)W[2 * s2 + 1][0], false, false);
      i32x2 r2 = __builtin_amdgcn_permlane32_swap((int)W[2 * s2][1], (int)W[2 * s2 + 1][1], false, false);
      u32x4 wq = {(u32)r1.x, (u32)r2.x, (u32)r1.y, (u32)r2.y};
      const bf16x8 pb = __builtin_bit_cast(bf16x8, wq);
      bf16x8 v0 = ld8(&lds[B0 + aV0[s2]]);
      bf16x8 v1 = ld8(&lds[B0 + aV1[s2]]);
      accO0 = mfma32(v0, pb, accO0);
      accO1 = mfma32(v1, pb, accO1);
      accLP = mfma32(ones, pb, accLP);
    }
  };

  stage(0, 0);
  __syncthreads();
#pragma unroll 1
  for (int t2 = 0; t2 < 32; ++t2) {
    stage(4096, 2 * t2 + 1);
    body(0);
    __syncthreads();
    if (t2 < 31) stage(0, 2 * t2 + 2);
    body(4096);
    __syncthreads();
  }

  // write raw partials: opart[z][bh][qt][d 64][q 128], lp[z][bh][qt][q 128]
  const size_t obase = ((size_t)z * 768 + bh * 32 + blockIdx.x) * 8192;
#pragma unroll
  for (int dt = 0; dt < 2; ++dt) {
    const f32x16 a = dt ? accO1 : accO0;
#pragma unroll
    for (int rq = 0; rq < 4; ++rq)
#pragma unroll
      for (int j = 0; j < 4; ++j) {
        const int d = dt * 32 + 8 * rq + 4 * hi + j;
        opart[obase + (size_t)d * 128 + w * 32 + l5] = a[rq * 4 + j];
      }
  }
  if (hi == 0)
    lppart[(size_t)z * 98304 + (size_t)(bh * 32 + blockIdx.x) * 128 + w * 32 + l5] =
        accLP[0];
}

// ---------------------------------------------------------------- merge halves
// ctx[b][qrow][h*64+d] = (o1+o2) / (l1+l2), bf16. 768 blocks x 128 threads.
__global__ void merge_halves(const float* __restrict__ opart,
                             const float* __restrict__ lppart,
                             u16* __restrict__ ctx) {
  const int blk = blockIdx.x;  // bh*32 + qt
  const int bh = blk >> 5, qt = blk & 31;
  const int q = threadIdx.x;   // 0..127
  const float l = lppart[(size_t)blk * 128 + q] + lppart[98304 + (size_t)blk * 128 + q];
  const float inv = __builtin_amdgcn_rcpf(l);
  const size_t o1 = (size_t)blk * 8192 + q;
  const size_t o2 = o1 + 6291456;
  const int b = bh / 12, h = bh % 12;
  u16* crow = ctx + ((size_t)b * 4096 + qt * 128 + q) * 768 + h * 64;
#pragma unroll
  for (int d0 = 0; d0 < 8; ++d0) {
    float o[8];
#pragma unroll
    for (int j = 0; j < 8; ++j) {
      const size_t off = (size_t)(d0 * 8 + j) * 128;
      o[j] = (opart[o1 + off] + opart[o2 + off]) * inv;
    }
    u32x4 pkv = {pk2(o[0], o[1]), pk2(o[2], o[3]), pk2(o[4], o[5]), pk2(o[6], o[7])};
    *(u32x4*)&crow[d0 * 8] = pkv;
  }
}

// ---------------------------------------------------------------- launcher
extern "C" void kernel_launch(void* const* d_in, const int* in_sizes, int n_in,
                              void* d_out, int out_size, void* d_ws, size_t ws_size,
                              hipStream_t stream) {
  constexpr int NQKV = 2 * 4096 * 768;
  const float* q = (const float*)d_in[0];
  const float* k = (const float*)d_in[1];
  const float* v = (const float*)d_in[2];
  const float* Wq = (const float*)d_in[3];
  const float* bq = (const float*)d_in[4];
  const float* Wk = (const float*)d_in[5];
  const float* bk = (const float*)d_in[6];
  const float* Wv = (const float*)d_in[7];
  const float* bv = (const float*)d_in[8];
  const float* Wo = (const float*)d_in[9];
  const float* bo = (const float*)d_in[10];

  char* p = (char*)d_ws;
  auto take = [&](size_t n) -> u16* {  // n u16 elements
    u16* r = (u16*)p;
    p += (n * 2 + 255) & ~(size_t)255;
    return r;
  };
  u16 *qh = take(NQKV), *kh = take(NQKV), *vt = take(NQKV), *ctx = take(NQKV);
  float* opart = (float*)take(2u * 12582912u);  // 2 halves x 6291456 f32
  float* lppart = (float*)take(2u * 196608u);   // 2 halves x 98304 f32

  const float qscale = 0.18033688011112042f;  // log2(e) / sqrt(64)
  gemm_qkv<<<dim3(64, 6, 3), 256, 0, stream>>>(
      q, k, v, Wq, Wk, Wv, bq, bk, bv, qh, kh, vt, qscale);
  flash_attn<<<dim3(32, 24, 2), 256, 0, stream>>>(qh, kh, vt, opart, lppart);
  merge_halves<<<768, 128, 0, stream>>>(opart, lppart, ctx);
  gemm_out<<<dim3(64, 6), 256, 0, stream>>>(ctx, Wo, bo, (float*)d_out);
}